// Round 19
// baseline (1048.212 us; speedup 1.0000x reference)
//
#include <hip/hip_runtime.h>
#include <hip/hip_bf16.h>
#include <cstdint>
#include <cstddef>
#include <math.h>

// ---------- types ----------
typedef __attribute__((ext_vector_type(8))) short bf16x8;
typedef __attribute__((ext_vector_type(4))) float f32x4;
typedef __attribute__((ext_vector_type(4))) short s16x4;

static __device__ __forceinline__ short f2bf(float f) {
  union { __hip_bfloat16 b; short s; } u;
  u.b = __float2bfloat16(f);
  return u.s;
}

static __device__ __forceinline__ float bf2f(short s) {
  union { unsigned u; float f; } v;
  v.u = ((unsigned)(unsigned short)s) << 16;
  return v.f;
}

static __device__ __forceinline__ void gload_lds16(const short* g, short* l) {
  __builtin_amdgcn_global_load_lds((const __attribute__((address_space(1))) void*)g,
                                   (__attribute__((address_space(3))) void*)l,
                                   16, 0, 0);
}

// ---------- fp32 -> bf16 convert (plain, MoE weights) ----------
__global__ __launch_bounds__(256) void cvt_k(const float* __restrict__ src,
                                             short* __restrict__ dst, long n4) {
  long i = (long)blockIdx.x * blockDim.x + threadIdx.x;
  long stride = (long)gridDim.x * blockDim.x;
  for (; i < n4; i += stride) {
    float4 v = ((const float4*)src)[i];
    s16x4 o;
    o.x = f2bf(v.x); o.y = f2bf(v.y); o.z = f2bf(v.z); o.w = f2bf(v.w);
    ((s16x4*)dst)[i] = o;
  }
}

// ---------- fused hi/lo split for 9 attention tensors (one launch) ----------
__global__ __launch_bounds__(256) void cvt2multi_k(
    const float* s0, const float* s1, const float* s2, const float* s3,
    const float* s4, const float* s5, const float* s6, const float* s7,
    const float* s8, short* __restrict__ hi, short* __restrict__ lo) {
  const int y = blockIdx.y;
  const long n4 = (y < 8) ? 262144 : 65536;
  long i = (long)blockIdx.x * 256 + threadIdx.x;
  if (i >= n4) return;
  const float* src;
  switch (y) {
    case 0: src = s0; break; case 1: src = s1; break;
    case 2: src = s2; break; case 3: src = s3; break;
    case 4: src = s4; break; case 5: src = s5; break;
    case 6: src = s6; break; case 7: src = s7; break;
    default: src = s8; break;
  }
  float4 v = ((const float4*)src)[i];
  s16x4 h, l;
  h.x = f2bf(v.x); l.x = f2bf(v.x - bf2f(h.x));
  h.y = f2bf(v.y); l.y = f2bf(v.y - bf2f(h.y));
  h.z = f2bf(v.z); l.z = f2bf(v.z - bf2f(h.z));
  h.w = f2bf(v.w); l.w = f2bf(v.w - bf2f(h.w));
  const long o = (long)y * 262144 + i;
  ((s16x4*)hi)[o] = h;
  ((s16x4*)lo)[o] = l;
}

// ---------- RMSNorm fp32 -> bf16 hi/lo split (attention norms) ----------
__global__ __launch_bounds__(256) void rms2_k(const float* __restrict__ x,
                                              const float* __restrict__ w,
                                              short* __restrict__ hi,
                                              short* __restrict__ lo) {
  const int row = blockIdx.x, tid = threadIdx.x;
  const float* xr = x + (size_t)row * 1024;
  float4 v = *(const float4*)&xr[tid * 4];
  float ss = v.x * v.x + v.y * v.y + v.z * v.z + v.w * v.w;
#pragma unroll
  for (int off = 32; off; off >>= 1) ss += __shfl_down(ss, off);
  __shared__ float red[4];
  if ((tid & 63) == 0) red[tid >> 6] = ss;
  __syncthreads();
  float rs = rsqrtf((red[0] + red[1] + red[2] + red[3]) * (1.f / 1024.f) + 1e-5f);
  float4 wv = *(const float4*)&w[tid * 4];
  float o0 = v.x * rs * wv.x, o1 = v.y * rs * wv.y;
  float o2 = v.z * rs * wv.z, o3 = v.w * rs * wv.w;
  s16x4 h, l;
  h.x = f2bf(o0); l.x = f2bf(o0 - bf2f(h.x));
  h.y = f2bf(o1); l.y = f2bf(o1 - bf2f(h.y));
  h.z = f2bf(o2); l.z = f2bf(o2 - bf2f(h.z));
  h.w = f2bf(o3); l.w = f2bf(o3 - bf2f(h.w));
  const size_t ib = (size_t)row * 1024 + tid * 4;
  *(s16x4*)&hi[ib] = h;
  *(s16x4*)&lo[ib] = l;
}

// ---------- bf16x3 split MFMA GEMM (upstream): 8 waves/512thr, BK=32 + XOR swizzle ----------
template <int EPI>
__global__ __launch_bounds__(512)
void gemm3_k(const short* __restrict__ Ah, const short* __restrict__ Al,
             const short* __restrict__ Bh, const short* __restrict__ Bl,
             float* __restrict__ C, const float* __restrict__ resid,
             short* __restrict__ Ch, short* __restrict__ Cl,
             int M, int N, int K) {
  __shared__ short sAh[128 * 32];
  __shared__ short sAl[128 * 32];
  __shared__ short sBh[128 * 32];
  __shared__ short sBl[128 * 32];

  const int bn = blockIdx.x, bm = blockIdx.y;
  const int tid = threadIdx.x;
  const int lane = tid & 63, wid = tid >> 6;
  const int wr = wid >> 2, wc = wid & 3;
  const int lr = lane & 15, lg = lane >> 4;
  const int rch = lane >> 2;
  const int cch = (((lane & 3) ^ (rch & 3)) << 3);
  const int sw = ((lg ^ (lr & 3)) << 3);

  const int ra = bm * 128 + wid * 16 + rch;
  const int rb = bn * 128 + wid * 16 + rch;

  f32x4 acc[4][2];
#pragma unroll
  for (int m = 0; m < 4; m++)
#pragma unroll
    for (int n = 0; n < 2; n++) acc[m][n] = (f32x4){0.f, 0.f, 0.f, 0.f};

  const int nk = K >> 5;
  for (int kt = 0; kt < nk; ++kt) {
    __syncthreads();
    const int colk = (kt << 5) + cch;
    gload_lds16(Ah + (size_t)ra * K + colk, &sAh[wid * 512]);
    gload_lds16(Al + (size_t)ra * K + colk, &sAl[wid * 512]);
    gload_lds16(Bh + (size_t)rb * K + colk, &sBh[wid * 512]);
    gload_lds16(Bl + (size_t)rb * K + colk, &sBl[wid * 512]);
    __syncthreads();
    bf16x8 ah[4], al[4], bh[2], bl[2];
#pragma unroll
    for (int m = 0; m < 4; m++) {
      const int o = (wr * 64 + m * 16 + lr) * 32 + sw;
      ah[m] = *(const bf16x8*)&sAh[o];
      al[m] = *(const bf16x8*)&sAl[o];
    }
#pragma unroll
    for (int n = 0; n < 2; n++) {
      const int o = (wc * 32 + n * 16 + lr) * 32 + sw;
      bh[n] = *(const bf16x8*)&sBh[o];
      bl[n] = *(const bf16x8*)&sBl[o];
    }
#pragma unroll
    for (int m = 0; m < 4; m++)
#pragma unroll
      for (int n = 0; n < 2; n++) {
        acc[m][n] = __builtin_amdgcn_mfma_f32_16x16x32_bf16(ah[m], bh[n], acc[m][n], 0, 0, 0);
        acc[m][n] = __builtin_amdgcn_mfma_f32_16x16x32_bf16(al[m], bh[n], acc[m][n], 0, 0, 0);
        acc[m][n] = __builtin_amdgcn_mfma_f32_16x16x32_bf16(ah[m], bl[n], acc[m][n], 0, 0, 0);
      }
  }

#pragma unroll
  for (int m = 0; m < 4; m++) {
    const int rl = bm * 128 + wr * 64 + m * 16 + lg * 4;
#pragma unroll
    for (int n = 0; n < 2; n++) {
      f32x4 v = acc[m][n];
      const int col = bn * 128 + wc * 32 + n * 16 + lr;
#pragma unroll
      for (int j = 0; j < 4; j++) {
        const size_t idx = (size_t)(rl + j) * N + col;
        if (EPI == 0) {
          C[idx] = v[j];
        } else if (EPI == 2) {
          C[idx] = v[j] + resid[idx];
        } else {
          short hh = f2bf(v[j]);
          Ch[idx] = hh;
          Cl[idx] = f2bf(v[j] - bf2f(hh));
        }
      }
    }
  }
}

// ---------- bf16x3 MFMA flash attention (Q hi/lo in REGISTERS; K ld=72) ----------
template <bool CAUSAL>
__global__ __launch_bounds__(256)
void attn3_k(const short* __restrict__ Qh, const short* __restrict__ Ql, int ldq,
             const short* __restrict__ Kh, const short* __restrict__ Kl, int ldk,
             const short* __restrict__ Vh, const short* __restrict__ Vl, int ldv,
             short* __restrict__ Oh, short* __restrict__ Ol, int ldo,
             int Tq, int Tkv, float scale) {
  __shared__ short sKh[64 * 72], sKl[64 * 72];
  __shared__ short sVh[64 * 72], sVl[64 * 72];
  __shared__ short sPh[4][16 * 72], sPl[4][16 * 72];

  const int idx = blockIdx.x;
  const int qb = 15 - (idx >> 6);
  const int h = (idx >> 2) & 15;
  const int b = idx & 3;
  const int tid = threadIdx.x, lane = tid & 63, wv = tid >> 6;
  const int hoff = h * 64;
  const int lr = lane & 15, lg = lane >> 4;
  const int qlo = wv * 16;

  bf16x8 qhf[2], qlf[2];
  {
    const size_t qrow = (size_t)(b * Tq + qb * 64 + qlo + lr) * ldq + hoff;
#pragma unroll
    for (int ks = 0; ks < 2; ks++) {
      qhf[ks] = *(const bf16x8*)&Qh[qrow + ks * 32 + lg * 8];
      qlf[ks] = *(const bf16x8*)&Ql[qrow + ks * 32 + lg * 8];
    }
  }

  float m_run = -1e30f, l_run = 0.f;
  f32x4 o[4];
#pragma unroll
  for (int n = 0; n < 4; n++) o[n] = (f32x4){0.f, 0.f, 0.f, 0.f};

  const int ntiles = CAUSAL ? (qb + 1) : (Tkv >> 6);
  for (int kt = 0; kt < ntiles; ++kt) {
    __syncthreads();
#pragma unroll
    for (int j = 0; j < 2; j++) {
      int c = j * 256 + tid;
      int row = c >> 3, col = (c & 7) << 3;
      size_t gk = (size_t)(b * Tkv + kt * 64 + row) * ldk + hoff + col;
      *(bf16x8*)&sKh[row * 72 + col] = *(const bf16x8*)&Kh[gk];
      *(bf16x8*)&sKl[row * 72 + col] = *(const bf16x8*)&Kl[gk];
      size_t gv = (size_t)(b * Tkv + kt * 64 + row) * ldv + hoff + col;
      bf16x8 vh = *(const bf16x8*)&Vh[gv];
      bf16x8 vl = *(const bf16x8*)&Vl[gv];
#pragma unroll
      for (int i = 0; i < 8; i++) {
        sVh[(col + i) * 72 + row] = vh[i];
        sVl[(col + i) * 72 + row] = vl[i];
      }
    }
    __syncthreads();

    f32x4 st[4];
#pragma unroll
    for (int jk = 0; jk < 4; jk++) st[jk] = (f32x4){0.f, 0.f, 0.f, 0.f};
#pragma unroll
    for (int ks = 0; ks < 2; ks++) {
#pragma unroll
      for (int jk = 0; jk < 4; jk++) {
        const int o2 = (jk * 16 + lr) * 72 + ks * 32 + lg * 8;
        bf16x8 kh = *(const bf16x8*)&sKh[o2];
        bf16x8 kl = *(const bf16x8*)&sKl[o2];
        st[jk] = __builtin_amdgcn_mfma_f32_16x16x32_bf16(kh, qhf[ks], st[jk], 0, 0, 0);
        st[jk] = __builtin_amdgcn_mfma_f32_16x16x32_bf16(kl, qhf[ks], st[jk], 0, 0, 0);
        st[jk] = __builtin_amdgcn_mfma_f32_16x16x32_bf16(kh, qlf[ks], st[jk], 0, 0, 0);
      }
    }

    const int qg = qb * 64 + qlo + lr;
    float s[16];
    float tmax = -1e30f;
#pragma unroll
    for (int jk = 0; jk < 4; jk++)
#pragma unroll
      for (int r2 = 0; r2 < 4; r2++) {
        float xv = st[jk][r2] * scale;
        if (CAUSAL && kt == qb) {
          int kvidx = kt * 64 + jk * 16 + lg * 4 + r2;
          if (kvidx > qg) xv = -1e30f;
        }
        s[jk * 4 + r2] = xv;
        tmax = fmaxf(tmax, xv);
      }
    tmax = fmaxf(tmax, __shfl_xor(tmax, 16));
    tmax = fmaxf(tmax, __shfl_xor(tmax, 32));
    float m_new = fmaxf(m_run, tmax);
    float alpha = __expf(m_run - m_new);
    float tsum = 0.f;
#pragma unroll
    for (int i = 0; i < 16; i++) {
      float ev = (s[i] <= -1e29f) ? 0.f : __expf(s[i] - m_new);
      s[i] = ev;
      tsum += ev;
    }
    tsum += __shfl_xor(tsum, 16);
    tsum += __shfl_xor(tsum, 32);
    l_run = l_run * alpha + tsum;
    m_run = m_new;

    short* pwh = &sPh[wv][0];
    short* pwl = &sPl[wv][0];
#pragma unroll
    for (int jk = 0; jk < 4; jk++) {
      s16x4 ph, pl;
      float e0 = s[jk * 4 + 0], e1 = s[jk * 4 + 1], e2 = s[jk * 4 + 2], e3 = s[jk * 4 + 3];
      ph.x = f2bf(e0); pl.x = f2bf(e0 - bf2f(ph.x));
      ph.y = f2bf(e1); pl.y = f2bf(e1 - bf2f(ph.y));
      ph.z = f2bf(e2); pl.z = f2bf(e2 - bf2f(ph.z));
      ph.w = f2bf(e3); pl.w = f2bf(e3 - bf2f(ph.w));
      *(s16x4*)&pwh[lr * 72 + jk * 16 + lg * 4] = ph;
      *(s16x4*)&pwl[lr * 72 + jk * 16 + lg * 4] = pl;
    }
#pragma unroll
    for (int r2 = 0; r2 < 4; r2++) {
      float al = __shfl(alpha, lg * 4 + r2);
#pragma unroll
      for (int db = 0; db < 4; db++) o[db][r2] *= al;
    }
    __syncthreads();

#pragma unroll
    for (int ks = 0; ks < 2; ks++) {
      bf16x8 pah = *(const bf16x8*)&pwh[lr * 72 + ks * 32 + lg * 8];
      bf16x8 pal = *(const bf16x8*)&pwl[lr * 72 + ks * 32 + lg * 8];
#pragma unroll
      for (int db = 0; db < 4; db++) {
        const int o2 = (db * 16 + lr) * 72 + ks * 32 + lg * 8;
        bf16x8 vfh = *(const bf16x8*)&sVh[o2];
        bf16x8 vfl = *(const bf16x8*)&sVl[o2];
        o[db] = __builtin_amdgcn_mfma_f32_16x16x32_bf16(pah, vfh, o[db], 0, 0, 0);
        o[db] = __builtin_amdgcn_mfma_f32_16x16x32_bf16(pal, vfh, o[db], 0, 0, 0);
        o[db] = __builtin_amdgcn_mfma_f32_16x16x32_bf16(pah, vfl, o[db], 0, 0, 0);
      }
    }
  }

  float rinv = 1.f / l_run;
#pragma unroll
  for (int r2 = 0; r2 < 4; r2++) {
    float inv = __shfl(rinv, lg * 4 + r2);
    int token = b * Tq + qb * 64 + qlo + lg * 4 + r2;
#pragma unroll
    for (int db = 0; db < 4; db++) {
      float vv = o[db][r2] * inv;
      short hh = f2bf(vv);
      const size_t ob = (size_t)token * ldo + hoff + db * 16 + lr;
      Oh[ob] = hh;
      Ol[ob] = f2bf(vv - bf2f(hh));
    }
  }
}

// ---------- bf16 MFMA GEMM (MoE): 16 waves/1024thr, 128x256 tile, BK=64, swizzle ----------
// Wave grid 2(M)x8(N); per-wave 64x32 output -> acc 4x2 f32x4. Halves A re-reads.
// MODE 1: A rows gathered via row_map. MODE 2: A rows contiguous from offs[e].
// EPI 1: silu->bf16. EPI 3: bf16 store.
template <int EPI, int MODE>
__global__ __launch_bounds__(1024)
void gemm_bt_k(const short* __restrict__ A, const short* __restrict__ B,
               void* C, int M, int N, int K,
               const int* __restrict__ row_map,
               const int* __restrict__ counts,
               const int* __restrict__ offs) {
  __shared__ short sA[128 * 64];
  __shared__ short sB[256 * 64];
  __shared__ int sRow[128];

  const int tid = threadIdx.x;
  const int bn = blockIdx.x, bm = blockIdx.y;
  const int e = blockIdx.z;
  const int cnt = counts[e];
  const int base = offs[e];
  if (bm * 128 >= cnt) return;
  const short* Bp = B + (size_t)e * N * K;

  const int lane = tid & 63, wid = tid >> 6;     // wid 0..15
  const int wr = wid >> 3, wc = wid & 7;         // 2M x 8N
  const int lr = lane & 15, lg = lane >> 4;
  const int lrow = lane >> 3;
  const int lcc = ((lane & 7) ^ lrow) << 3;

  if (MODE == 1) {
    if (tid < 128) {
      int r = bm * 128 + tid;
      sRow[tid] = (r < cnt) ? row_map[base + r] : row_map[base];
    }
    __syncthreads();
  }
  // A: wave stages rows wid*8 + lrow (128 rows total); B: rows wid*16 + i*8 + lrow (256)
  int rag, rbg[2];
  {
    const int rla = wid * 8 + lrow;
    if (MODE == 2) {
      rag = base + ((bm * 128 + rla < cnt) ? (bm * 128 + rla) : 0);
    } else {
      rag = sRow[rla];
    }
#pragma unroll
    for (int i = 0; i < 2; i++) rbg[i] = bn * 256 + wid * 16 + i * 8 + lrow;
  }

  f32x4 acc[4][2];
#pragma unroll
  for (int m = 0; m < 4; m++)
#pragma unroll
    for (int n = 0; n < 2; n++) acc[m][n] = (f32x4){0.f, 0.f, 0.f, 0.f};

  const int nk = K >> 6;
  for (int kt = 0; kt < nk; ++kt) {
    __syncthreads();
    const int colk = (kt << 6) + lcc;
    gload_lds16(A + (size_t)rag * K + colk, &sA[(wid * 8) * 64]);
#pragma unroll
    for (int i = 0; i < 2; i++)
      gload_lds16(Bp + (size_t)rbg[i] * K + colk, &sB[(wid * 16 + i * 8) * 64]);
    __syncthreads();
#pragma unroll
    for (int ks = 0; ks < 2; ks++) {
      const int sw = ((((ks << 2) + lg) ^ (lr & 7)) << 3);
      bf16x8 a[4], b[2];
#pragma unroll
      for (int m = 0; m < 4; m++)
        a[m] = *(const bf16x8*)&sA[(wr * 64 + m * 16 + lr) * 64 + sw];
#pragma unroll
      for (int n = 0; n < 2; n++)
        b[n] = *(const bf16x8*)&sB[(wc * 32 + n * 16 + lr) * 64 + sw];
#pragma unroll
      for (int m = 0; m < 4; m++)
#pragma unroll
        for (int n = 0; n < 2; n++)
          acc[m][n] = __builtin_amdgcn_mfma_f32_16x16x32_bf16(a[m], b[n], acc[m][n], 0, 0, 0);
    }
  }

#pragma unroll
  for (int m = 0; m < 4; m++) {
    const int rl = wr * 64 + m * 16 + lg * 4;
#pragma unroll
    for (int n = 0; n < 2; n++) {
      f32x4 v = acc[m][n];
      const int col = bn * 256 + wc * 32 + n * 16 + lr;
#pragma unroll
      for (int j = 0; j < 4; j++) {
        const int rloc = bm * 128 + rl + j;
        if (rloc >= cnt) continue;
        const size_t idx = (size_t)(base + rloc) * N + col;
        float xv = v[j];
        if (EPI == 1) {
          float s = xv / (1.f + __expf(-xv));
          ((short*)C)[idx] = f2bf(s);
        } else {
          ((short*)C)[idx] = f2bf(xv);
        }
      }
    }
  }
}

// ---------- MoE gating FP64, FUSED with rms->xn write ----------
__global__ __launch_bounds__(256) void gate_k(const float* __restrict__ H,
                                              const float* __restrict__ w3,
                                              const float* __restrict__ gw,
                                              short* __restrict__ xn,
                                              int* counts, int* tok_e, int* tok_s,
                                              float* tok_g) {
  const int token = blockIdx.x * 4 + (threadIdx.x >> 6);
  const int lane = threadIdx.x & 63;
  const float* xr = H + (size_t)token * 1024;
  float4 xv4[4], w34[4];
  double a[8] = {0, 0, 0, 0, 0, 0, 0, 0};
  double ss = 0.0;
#pragma unroll
  for (int i = 0; i < 4; i++) {
    xv4[i] = *(const float4*)&xr[i * 256 + lane * 4];
    w34[i] = *(const float4*)&w3[i * 256 + lane * 4];
    float4 xv = xv4[i], w3v = w34[i];
    ss += (double)xv.x * xv.x + (double)xv.y * xv.y + (double)xv.z * xv.z + (double)xv.w * xv.w;
    double xw0 = (double)xv.x * (double)w3v.x, xw1 = (double)xv.y * (double)w3v.y;
    double xw2 = (double)xv.z * (double)w3v.z, xw3 = (double)xv.w * (double)w3v.w;
#pragma unroll
    for (int e = 0; e < 8; e++) {
      float4 wv = *(const float4*)&gw[e * 1024 + i * 256 + lane * 4];
      a[e] += xw0 * wv.x + xw1 * wv.y + xw2 * wv.z + xw3 * wv.w;
    }
  }
#pragma unroll
  for (int off = 32; off; off >>= 1) ss += __shfl_xor(ss, off);
#pragma unroll
  for (int off = 32; off; off >>= 1) {
#pragma unroll
    for (int e = 0; e < 8; e++) a[e] += __shfl_down(a[e], off);
  }
  const double rs_d = 1.0 / sqrt(ss * (1.0 / 1024.0) + 1e-5);
  const float rs = (float)rs_d;
#pragma unroll
  for (int i = 0; i < 4; i++) {
    s16x4 ob;
    ob.x = f2bf(xv4[i].x * rs * w34[i].x);
    ob.y = f2bf(xv4[i].y * rs * w34[i].y);
    ob.z = f2bf(xv4[i].z * rs * w34[i].z);
    ob.w = f2bf(xv4[i].w * rs * w34[i].w);
    *(s16x4*)&xn[(size_t)token * 1024 + i * 256 + lane * 4] = ob;
  }
  if (lane == 0) {
    double v0 = a[0]; int i0 = 0;
#pragma unroll
    for (int e = 1; e < 8; e++) if (a[e] > v0) { v0 = a[e]; i0 = e; }
    double v1 = -1e300; int i1 = 0;
#pragma unroll
    for (int e = 0; e < 8; e++) if (e != i0 && a[e] > v1) { v1 = a[e]; i1 = e; }
    double t = exp((v1 - v0) * rs_d);
    double g0 = 1.0 / (1.0 + t);
    int s0 = atomicAdd(&counts[i0], 1);
    int s1 = atomicAdd(&counts[i1], 1);
    tok_e[2 * token] = i0; tok_e[2 * token + 1] = i1;
    tok_s[2 * token] = s0; tok_s[2 * token + 1] = s1;
    tok_g[2 * token] = (float)g0; tok_g[2 * token + 1] = (float)(1.0 - g0);
  }
}

__global__ void offsets_k(int* counts, int* offs) {
  if (threadIdx.x == 0 && blockIdx.x == 0) {
    counts[8] = 4096;
    int s = 0;
    for (int e = 0; e < 9; e++) { offs[e] = s; s += counts[e]; }
  }
}

__global__ __launch_bounds__(256) void build_rows_k(const int* __restrict__ offs,
                                                    const int* __restrict__ tok_e,
                                                    const int* __restrict__ tok_s,
                                                    int* __restrict__ row_map,
                                                    int* __restrict__ tok_row) {
  int n = blockIdx.x * 256 + threadIdx.x;
  int e0 = tok_e[2 * n], e1 = tok_e[2 * n + 1];
  int r0 = offs[e0] + tok_s[2 * n], r1 = offs[e1] + tok_s[2 * n + 1];
  row_map[r0] = n; row_map[r1] = n;
  row_map[8192 + n] = n;
  tok_row[2 * n] = r0; tok_row[2 * n + 1] = r1;
}

// ---------- final combine: out = H + eo_shared + g0*eo0 + g1*eo1 (eo bf16) ----------
__global__ __launch_bounds__(256) void combine_k(const float* __restrict__ H,
                                                 const short* __restrict__ eo,
                                                 const int* __restrict__ tok_row,
                                                 const float* __restrict__ tok_g,
                                                 float* __restrict__ out) {
  const int n = blockIdx.x, t = threadIdx.x;
  const int r0 = tok_row[2 * n], r1 = tok_row[2 * n + 1];
  const float g0 = tok_g[2 * n], g1 = tok_g[2 * n + 1];
  const size_t ib = (size_t)n * 1024 + t * 4;
  float4 hv = *(const float4*)&H[ib];
  s16x4 sv = *(const s16x4*)&eo[(size_t)(8192 + n) * 1024 + t * 4];
  s16x4 a0 = *(const s16x4*)&eo[(size_t)r0 * 1024 + t * 4];
  s16x4 a1 = *(const s16x4*)&eo[(size_t)r1 * 1024 + t * 4];
  float4 ov;
  ov.x = hv.x + bf2f(sv.x) + g0 * bf2f(a0.x) + g1 * bf2f(a1.x);
  ov.y = hv.y + bf2f(sv.y) + g0 * bf2f(a0.y) + g1 * bf2f(a1.y);
  ov.z = hv.z + bf2f(sv.z) + g0 * bf2f(a0.z) + g1 * bf2f(a1.z);
  ov.w = hv.w + bf2f(sv.w) + g0 * bf2f(a0.w) + g1 * bf2f(a1.w);
  *(float4*)&out[ib] = ov;
}

// ---------- host ----------
extern "C" void kernel_launch(void* const* d_in, const int* in_sizes, int n_in,
                              void* d_out, int out_size, void* d_ws, size_t ws_size,
                              hipStream_t stream) {
  (void)in_sizes; (void)n_in; (void)out_size;
  const float* x     = (const float*)d_in[0];
  const float* enc   = (const float*)d_in[1];
  const float* n1w   = (const float*)d_in[4];
  const float* n2w   = (const float*)d_in[5];
  const float* n3w   = (const float*)d_in[6];
  const float* sa_wq = (const float*)d_in[7];
  const float* sa_wk = (const float*)d_in[8];
  const float* sa_wv = (const float*)d_in[9];
  const float* sa_wo = (const float*)d_in[10];
  const float* ca_wq = (const float*)d_in[11];
  const float* ca_wk = (const float*)d_in[12];
  const float* ca_wv = (const float*)d_in[13];
  const float* ca_wo = (const float*)d_in[14];
  const float* gw    = (const float*)d_in[15];
  const float* e_w1  = (const float*)d_in[16];
  const float* e_w2  = (const float*)d_in[17];
  const float* s_w1  = (const float*)d_in[18];
  const float* s_w2  = (const float*)d_in[19];
  float* out = (float*)d_out;

  char* p = (char*)d_ws;
  size_t off = 0;
  auto alloc = [&](size_t bytes) -> void* {
    void* r = p + off;
    off += (bytes + 255) & ~(size_t)255;
    return r;
  };
  short* w_all1 = (short*)alloc(9LL * 4096 * 1024 * 2);
  short* w_all2 = (short*)alloc(9LL * 1024 * 4096 * 2);
  short* xn     = (short*)alloc(4096LL * 1024 * 2);
  char*  U      = (char*)alloc(12288LL * 4096 * 2);
  short* hbuf   = (short*)U;
  float* Hb     = (float*)alloc(4096LL * 1024 * 4);
  short* eo     = (short*)alloc(12288LL * 1024 * 2);
  short* xh     = (short*)alloc(4096LL * 1024 * 2);
  short* xl     = (short*)alloc(4096LL * 1024 * 2);
  short* wsplH  = (short*)alloc(8650752LL * 2);
  short* wsplL  = (short*)alloc(8650752LL * 2);
  int*   counts = (int*)alloc(9 * 4);
  int*   offs   = (int*)alloc(9 * 4);
  int*   tok_e  = (int*)alloc(4096LL * 2 * 4);
  int*   tok_s  = (int*)alloc(4096LL * 2 * 4);
  float* tok_g  = (float*)alloc(4096LL * 2 * 4);
  int*   tok_row= (int*)alloc(4096LL * 2 * 4);
  int*   row_map= (int*)alloc(12288LL * 4);
  if (off > ws_size) return;

  short* wQKVh = wsplH;
  short* wQKVl = wsplL;
  short* wOh   = wsplH + 3145728;
  short* wOl   = wsplL + 3145728;
  short* wCQh  = wsplH + 4194304;
  short* wCQl  = wsplL + 4194304;
  short* wCKVh = wsplH + 5242880;
  short* wCKVl = wsplL + 5242880;
  short* wCOh  = wsplH + 7340032;
  short* wCOl  = wsplL + 7340032;
  short* ench  = wsplH + 8388608;
  short* encl  = wsplL + 8388608;

  short* qkvh = (short*)U;
  short* qkvl = qkvh + 4096LL * 3072;
  short* crossQh = (short*)U;
  short* crossQl = crossQh + 4096LL * 1024;
  short* encKVh  = crossQl + 4096LL * 1024;
  short* encKVl  = encKVh + 256LL * 2048;

  auto cvt = [&](const float* s, short* d, long n) {
    long n4 = n / 4;
    long g = (n4 + 255) / 256;
    int grid = (int)(g > 4096 ? 4096 : g);
    cvt_k<<<grid, 256, 0, stream>>>(s, d, n4);
  };

  cvt2multi_k<<<dim3(1024, 9), 256, 0, stream>>>(sa_wq, sa_wk, sa_wv, sa_wo,
      ca_wq, ca_wk, ca_wv, ca_wo, enc, wsplH, wsplL);

  cvt(e_w1, w_all1, 8L * 4096 * 1024);
  cvt(s_w1, w_all1 + 8L * 4096 * 1024, 4096L * 1024);
  cvt(e_w2, w_all2, 8L * 1024 * 4096);
  cvt(s_w2, w_all2 + 8L * 1024 * 4096, 1024L * 4096);

  // ---- self attention ----
  rms2_k<<<4096, 256, 0, stream>>>(x, n1w, xh, xl);
  gemm3_k<3><<<dim3(24, 32), 512, 0, stream>>>(xh, xl, wQKVh, wQKVl, nullptr, nullptr,
      qkvh, qkvl, 4096, 3072, 1024);
  attn3_k<true><<<1024, 256, 0, stream>>>(qkvh, qkvl, 3072,
      qkvh + 1024, qkvl + 1024, 3072, qkvh + 2048, qkvl + 2048, 3072,
      xh, xl, 1024, 1024, 1024, 0.125f);
  gemm3_k<2><<<dim3(8, 32), 512, 0, stream>>>(xh, xl, wOh, wOl, Hb, x,
      nullptr, nullptr, 4096, 1024, 1024);

  // ---- cross attention ----
  rms2_k<<<4096, 256, 0, stream>>>(Hb, n2w, xh, xl);
  gemm3_k<3><<<dim3(8, 32), 512, 0, stream>>>(xh, xl, wCQh, wCQl, nullptr, nullptr,
      crossQh, crossQl, 4096, 1024, 1024);
  gemm3_k<3><<<dim3(16, 2), 512, 0, stream>>>(ench, encl, wCKVh, wCKVl, nullptr, nullptr,
      encKVh, encKVl, 256, 2048, 1024);
  attn3_k<false><<<1024, 256, 0, stream>>>(crossQh, crossQl, 1024,
      encKVh, encKVl, 2048, encKVh + 1024, encKVl + 1024, 2048,
      xh, xl, 1024, 1024, 64, 0.125f);
  gemm3_k<2><<<dim3(8, 32), 512, 0, stream>>>(xh, xl, wCOh, wCOl, Hb, Hb,
      nullptr, nullptr, 4096, 1024, 1024);

  // ---- MoE: fused fp64 gate + rms->xn; 9-expert bf16 MFMA, 128x256 tile ----
  hipMemsetAsync(counts, 0, 8 * sizeof(int), stream);
  gate_k<<<1024, 256, 0, stream>>>(Hb, n3w, gw, xn, counts, tok_e, tok_s, tok_g);
  offsets_k<<<1, 1, 0, stream>>>(counts, offs);
  build_rows_k<<<16, 256, 0, stream>>>(offs, tok_e, tok_s, row_map, tok_row);
  gemm_bt_k<1, 1><<<dim3(16, 32, 9), 1024, 0, stream>>>(xn, w_all1, hbuf,
      4096, 4096, 1024, row_map, counts, offs);
  gemm_bt_k<3, 2><<<dim3(4, 32, 9), 1024, 0, stream>>>(hbuf, w_all2, eo,
      4096, 1024, 4096, row_map, counts, offs);

  combine_k<<<4096, 256, 0, stream>>>(Hb, eo, tok_row, tok_g, out);
}

// Round 20
// 936.402 us; speedup vs baseline: 1.1194x; 1.1194x over previous
//
#include <hip/hip_runtime.h>
#include <hip/hip_bf16.h>
#include <cstdint>
#include <cstddef>
#include <math.h>

// ---------- types ----------
typedef __attribute__((ext_vector_type(8))) short bf16x8;
typedef __attribute__((ext_vector_type(4))) float f32x4;
typedef __attribute__((ext_vector_type(4))) short s16x4;

static __device__ __forceinline__ short f2bf(float f) {
  union { __hip_bfloat16 b; short s; } u;
  u.b = __float2bfloat16(f);
  return u.s;
}

static __device__ __forceinline__ float bf2f(short s) {
  union { unsigned u; float f; } v;
  v.u = ((unsigned)(unsigned short)s) << 16;
  return v.f;
}

static __device__ __forceinline__ void gload_lds16(const short* g, short* l) {
  __builtin_amdgcn_global_load_lds((const __attribute__((address_space(1))) void*)g,
                                   (__attribute__((address_space(3))) void*)l,
                                   16, 0, 0);
}

// ---------- fp32 -> bf16 convert (plain, MoE weights) ----------
__global__ __launch_bounds__(256) void cvt_k(const float* __restrict__ src,
                                             short* __restrict__ dst, long n4) {
  long i = (long)blockIdx.x * blockDim.x + threadIdx.x;
  long stride = (long)gridDim.x * blockDim.x;
  for (; i < n4; i += stride) {
    float4 v = ((const float4*)src)[i];
    s16x4 o;
    o.x = f2bf(v.x); o.y = f2bf(v.y); o.z = f2bf(v.z); o.w = f2bf(v.w);
    ((s16x4*)dst)[i] = o;
  }
}

// ---------- fused hi/lo split for 9 attention tensors (one launch) ----------
__global__ __launch_bounds__(256) void cvt2multi_k(
    const float* s0, const float* s1, const float* s2, const float* s3,
    const float* s4, const float* s5, const float* s6, const float* s7,
    const float* s8, short* __restrict__ hi, short* __restrict__ lo) {
  const int y = blockIdx.y;
  const long n4 = (y < 8) ? 262144 : 65536;
  long i = (long)blockIdx.x * 256 + threadIdx.x;
  if (i >= n4) return;
  const float* src;
  switch (y) {
    case 0: src = s0; break; case 1: src = s1; break;
    case 2: src = s2; break; case 3: src = s3; break;
    case 4: src = s4; break; case 5: src = s5; break;
    case 6: src = s6; break; case 7: src = s7; break;
    default: src = s8; break;
  }
  float4 v = ((const float4*)src)[i];
  s16x4 h, l;
  h.x = f2bf(v.x); l.x = f2bf(v.x - bf2f(h.x));
  h.y = f2bf(v.y); l.y = f2bf(v.y - bf2f(h.y));
  h.z = f2bf(v.z); l.z = f2bf(v.z - bf2f(h.z));
  h.w = f2bf(v.w); l.w = f2bf(v.w - bf2f(h.w));
  const long o = (long)y * 262144 + i;
  ((s16x4*)hi)[o] = h;
  ((s16x4*)lo)[o] = l;
}

// ---------- RMSNorm fp32 -> bf16 hi/lo split (attention norms) ----------
__global__ __launch_bounds__(256) void rms2_k(const float* __restrict__ x,
                                              const float* __restrict__ w,
                                              short* __restrict__ hi,
                                              short* __restrict__ lo) {
  const int row = blockIdx.x, tid = threadIdx.x;
  const float* xr = x + (size_t)row * 1024;
  float4 v = *(const float4*)&xr[tid * 4];
  float ss = v.x * v.x + v.y * v.y + v.z * v.z + v.w * v.w;
#pragma unroll
  for (int off = 32; off; off >>= 1) ss += __shfl_down(ss, off);
  __shared__ float red[4];
  if ((tid & 63) == 0) red[tid >> 6] = ss;
  __syncthreads();
  float rs = rsqrtf((red[0] + red[1] + red[2] + red[3]) * (1.f / 1024.f) + 1e-5f);
  float4 wv = *(const float4*)&w[tid * 4];
  float o0 = v.x * rs * wv.x, o1 = v.y * rs * wv.y;
  float o2 = v.z * rs * wv.z, o3 = v.w * rs * wv.w;
  s16x4 h, l;
  h.x = f2bf(o0); l.x = f2bf(o0 - bf2f(h.x));
  h.y = f2bf(o1); l.y = f2bf(o1 - bf2f(h.y));
  h.z = f2bf(o2); l.z = f2bf(o2 - bf2f(h.z));
  h.w = f2bf(o3); l.w = f2bf(o3 - bf2f(h.w));
  const size_t ib = (size_t)row * 1024 + tid * 4;
  *(s16x4*)&hi[ib] = h;
  *(s16x4*)&lo[ib] = l;
}

// ---------- bf16x3 split MFMA GEMM (upstream): 8 waves/512thr, BK=32 + XOR swizzle ----------
// Wave grid 2(M)x4(N); per-wave 64x32 output -> acc 4x2 f32x4 for occupancy.
// EPI 0: fp32 store. EPI 2: fp32 +resid. EPI 3: bf16 hi/lo store (Ch/Cl).
template <int EPI>
__global__ __launch_bounds__(512)
void gemm3_k(const short* __restrict__ Ah, const short* __restrict__ Al,
             const short* __restrict__ Bh, const short* __restrict__ Bl,
             float* __restrict__ C, const float* __restrict__ resid,
             short* __restrict__ Ch, short* __restrict__ Cl,
             int M, int N, int K) {
  __shared__ short sAh[128 * 32];
  __shared__ short sAl[128 * 32];
  __shared__ short sBh[128 * 32];
  __shared__ short sBl[128 * 32];

  const int bn = blockIdx.x, bm = blockIdx.y;
  const int tid = threadIdx.x;
  const int lane = tid & 63, wid = tid >> 6;
  const int wr = wid >> 2, wc = wid & 3;
  const int lr = lane & 15, lg = lane >> 4;
  const int rch = lane >> 2;
  const int cch = (((lane & 3) ^ (rch & 3)) << 3);  // swizzled source col
  const int sw = ((lg ^ (lr & 3)) << 3);            // swizzled read slot

  const int ra = bm * 128 + wid * 16 + rch;
  const int rb = bn * 128 + wid * 16 + rch;

  f32x4 acc[4][2];
#pragma unroll
  for (int m = 0; m < 4; m++)
#pragma unroll
    for (int n = 0; n < 2; n++) acc[m][n] = (f32x4){0.f, 0.f, 0.f, 0.f};

  const int nk = K >> 5;
  for (int kt = 0; kt < nk; ++kt) {
    __syncthreads();
    const int colk = (kt << 5) + cch;
    gload_lds16(Ah + (size_t)ra * K + colk, &sAh[wid * 512]);
    gload_lds16(Al + (size_t)ra * K + colk, &sAl[wid * 512]);
    gload_lds16(Bh + (size_t)rb * K + colk, &sBh[wid * 512]);
    gload_lds16(Bl + (size_t)rb * K + colk, &sBl[wid * 512]);
    __syncthreads();
    bf16x8 ah[4], al[4], bh[2], bl[2];
#pragma unroll
    for (int m = 0; m < 4; m++) {
      const int o = (wr * 64 + m * 16 + lr) * 32 + sw;
      ah[m] = *(const bf16x8*)&sAh[o];
      al[m] = *(const bf16x8*)&sAl[o];
    }
#pragma unroll
    for (int n = 0; n < 2; n++) {
      const int o = (wc * 32 + n * 16 + lr) * 32 + sw;
      bh[n] = *(const bf16x8*)&sBh[o];
      bl[n] = *(const bf16x8*)&sBl[o];
    }
#pragma unroll
    for (int m = 0; m < 4; m++)
#pragma unroll
      for (int n = 0; n < 2; n++) {
        acc[m][n] = __builtin_amdgcn_mfma_f32_16x16x32_bf16(ah[m], bh[n], acc[m][n], 0, 0, 0);
        acc[m][n] = __builtin_amdgcn_mfma_f32_16x16x32_bf16(al[m], bh[n], acc[m][n], 0, 0, 0);
        acc[m][n] = __builtin_amdgcn_mfma_f32_16x16x32_bf16(ah[m], bl[n], acc[m][n], 0, 0, 0);
      }
  }

#pragma unroll
  for (int m = 0; m < 4; m++) {
    const int rl = bm * 128 + wr * 64 + m * 16 + lg * 4;
#pragma unroll
    for (int n = 0; n < 2; n++) {
      f32x4 v = acc[m][n];
      const int col = bn * 128 + wc * 32 + n * 16 + lr;
#pragma unroll
      for (int j = 0; j < 4; j++) {
        const size_t idx = (size_t)(rl + j) * N + col;
        if (EPI == 0) {
          C[idx] = v[j];
        } else if (EPI == 2) {
          C[idx] = v[j] + resid[idx];
        } else {
          short hh = f2bf(v[j]);
          Ch[idx] = hh;
          Cl[idx] = f2bf(v[j] - bf2f(hh));
        }
      }
    }
  }
}

// ---------- bf16x3 MFMA flash attention (Q hi/lo in REGISTERS; K ld=72) ----------
template <bool CAUSAL>
__global__ __launch_bounds__(256)
void attn3_k(const short* __restrict__ Qh, const short* __restrict__ Ql, int ldq,
             const short* __restrict__ Kh, const short* __restrict__ Kl, int ldk,
             const short* __restrict__ Vh, const short* __restrict__ Vl, int ldv,
             short* __restrict__ Oh, short* __restrict__ Ol, int ldo,
             int Tq, int Tkv, float scale) {
  __shared__ short sKh[64 * 72], sKl[64 * 72];
  __shared__ short sVh[64 * 72], sVl[64 * 72];
  __shared__ short sPh[4][16 * 72], sPl[4][16 * 72];

  const int idx = blockIdx.x;
  const int qb = 15 - (idx >> 6);
  const int h = (idx >> 2) & 15;
  const int b = idx & 3;
  const int tid = threadIdx.x, lane = tid & 63, wv = tid >> 6;
  const int hoff = h * 64;
  const int lr = lane & 15, lg = lane >> 4;
  const int qlo = wv * 16;

  bf16x8 qhf[2], qlf[2];
  {
    const size_t qrow = (size_t)(b * Tq + qb * 64 + qlo + lr) * ldq + hoff;
#pragma unroll
    for (int ks = 0; ks < 2; ks++) {
      qhf[ks] = *(const bf16x8*)&Qh[qrow + ks * 32 + lg * 8];
      qlf[ks] = *(const bf16x8*)&Ql[qrow + ks * 32 + lg * 8];
    }
  }

  float m_run = -1e30f, l_run = 0.f;
  f32x4 o[4];
#pragma unroll
  for (int n = 0; n < 4; n++) o[n] = (f32x4){0.f, 0.f, 0.f, 0.f};

  const int ntiles = CAUSAL ? (qb + 1) : (Tkv >> 6);
  for (int kt = 0; kt < ntiles; ++kt) {
    __syncthreads();
#pragma unroll
    for (int j = 0; j < 2; j++) {
      int c = j * 256 + tid;
      int row = c >> 3, col = (c & 7) << 3;
      size_t gk = (size_t)(b * Tkv + kt * 64 + row) * ldk + hoff + col;
      *(bf16x8*)&sKh[row * 72 + col] = *(const bf16x8*)&Kh[gk];
      *(bf16x8*)&sKl[row * 72 + col] = *(const bf16x8*)&Kl[gk];
      size_t gv = (size_t)(b * Tkv + kt * 64 + row) * ldv + hoff + col;
      bf16x8 vh = *(const bf16x8*)&Vh[gv];
      bf16x8 vl = *(const bf16x8*)&Vl[gv];
#pragma unroll
      for (int i = 0; i < 8; i++) {
        sVh[(col + i) * 72 + row] = vh[i];
        sVl[(col + i) * 72 + row] = vl[i];
      }
    }
    __syncthreads();

    f32x4 st[4];
#pragma unroll
    for (int jk = 0; jk < 4; jk++) st[jk] = (f32x4){0.f, 0.f, 0.f, 0.f};
#pragma unroll
    for (int ks = 0; ks < 2; ks++) {
#pragma unroll
      for (int jk = 0; jk < 4; jk++) {
        const int o2 = (jk * 16 + lr) * 72 + ks * 32 + lg * 8;
        bf16x8 kh = *(const bf16x8*)&sKh[o2];
        bf16x8 kl = *(const bf16x8*)&sKl[o2];
        st[jk] = __builtin_amdgcn_mfma_f32_16x16x32_bf16(kh, qhf[ks], st[jk], 0, 0, 0);
        st[jk] = __builtin_amdgcn_mfma_f32_16x16x32_bf16(kl, qhf[ks], st[jk], 0, 0, 0);
        st[jk] = __builtin_amdgcn_mfma_f32_16x16x32_bf16(kh, qlf[ks], st[jk], 0, 0, 0);
      }
    }

    const int qg = qb * 64 + qlo + lr;
    float s[16];
    float tmax = -1e30f;
#pragma unroll
    for (int jk = 0; jk < 4; jk++)
#pragma unroll
      for (int r2 = 0; r2 < 4; r2++) {
        float xv = st[jk][r2] * scale;
        if (CAUSAL && kt == qb) {
          int kvidx = kt * 64 + jk * 16 + lg * 4 + r2;
          if (kvidx > qg) xv = -1e30f;
        }
        s[jk * 4 + r2] = xv;
        tmax = fmaxf(tmax, xv);
      }
    tmax = fmaxf(tmax, __shfl_xor(tmax, 16));
    tmax = fmaxf(tmax, __shfl_xor(tmax, 32));
    float m_new = fmaxf(m_run, tmax);
    float alpha = __expf(m_run - m_new);
    float tsum = 0.f;
#pragma unroll
    for (int i = 0; i < 16; i++) {
      float ev = (s[i] <= -1e29f) ? 0.f : __expf(s[i] - m_new);
      s[i] = ev;
      tsum += ev;
    }
    tsum += __shfl_xor(tsum, 16);
    tsum += __shfl_xor(tsum, 32);
    l_run = l_run * alpha + tsum;
    m_run = m_new;

    short* pwh = &sPh[wv][0];
    short* pwl = &sPl[wv][0];
#pragma unroll
    for (int jk = 0; jk < 4; jk++) {
      s16x4 ph, pl;
      float e0 = s[jk * 4 + 0], e1 = s[jk * 4 + 1], e2 = s[jk * 4 + 2], e3 = s[jk * 4 + 3];
      ph.x = f2bf(e0); pl.x = f2bf(e0 - bf2f(ph.x));
      ph.y = f2bf(e1); pl.y = f2bf(e1 - bf2f(ph.y));
      ph.z = f2bf(e2); pl.z = f2bf(e2 - bf2f(ph.z));
      ph.w = f2bf(e3); pl.w = f2bf(e3 - bf2f(ph.w));
      *(s16x4*)&pwh[lr * 72 + jk * 16 + lg * 4] = ph;
      *(s16x4*)&pwl[lr * 72 + jk * 16 + lg * 4] = pl;
    }
#pragma unroll
    for (int r2 = 0; r2 < 4; r2++) {
      float al = __shfl(alpha, lg * 4 + r2);
#pragma unroll
      for (int db = 0; db < 4; db++) o[db][r2] *= al;
    }
    __syncthreads();

#pragma unroll
    for (int ks = 0; ks < 2; ks++) {
      bf16x8 pah = *(const bf16x8*)&pwh[lr * 72 + ks * 32 + lg * 8];
      bf16x8 pal = *(const bf16x8*)&pwl[lr * 72 + ks * 32 + lg * 8];
#pragma unroll
      for (int db = 0; db < 4; db++) {
        const int o2 = (db * 16 + lr) * 72 + ks * 32 + lg * 8;
        bf16x8 vfh = *(const bf16x8*)&sVh[o2];
        bf16x8 vfl = *(const bf16x8*)&sVl[o2];
        o[db] = __builtin_amdgcn_mfma_f32_16x16x32_bf16(pah, vfh, o[db], 0, 0, 0);
        o[db] = __builtin_amdgcn_mfma_f32_16x16x32_bf16(pal, vfh, o[db], 0, 0, 0);
        o[db] = __builtin_amdgcn_mfma_f32_16x16x32_bf16(pah, vfl, o[db], 0, 0, 0);
      }
    }
  }

  float rinv = 1.f / l_run;
#pragma unroll
  for (int r2 = 0; r2 < 4; r2++) {
    float inv = __shfl(rinv, lg * 4 + r2);
    int token = b * Tq + qb * 64 + qlo + lg * 4 + r2;
#pragma unroll
    for (int db = 0; db < 4; db++) {
      float vv = o[db][r2] * inv;
      short hh = f2bf(vv);
      const size_t ob = (size_t)token * ldo + hoff + db * 16 + lr;
      Oh[ob] = hh;
      Ol[ob] = f2bf(vv - bf2f(hh));
    }
  }
}

// ---------- bf16 MFMA GEMM (MoE): 8 waves/512thr, BK=64, swizzle, 64x32/wave ----------
template <int EPI, int MODE>
__global__ __launch_bounds__(512)
void gemm_bt_k(const short* __restrict__ A, const short* __restrict__ B,
               void* C, int M, int N, int K,
               const int* __restrict__ row_map,
               const int* __restrict__ counts,
               const int* __restrict__ offs) {
  __shared__ short sA[128 * 64];
  __shared__ short sB[128 * 64];
  __shared__ int sRow[128];

  const int tid = threadIdx.x;
  const int bn = blockIdx.x, bm = blockIdx.y;
  const int e = blockIdx.z;
  const int cnt = counts[e];
  const int base = offs[e];
  if (bm * 128 >= cnt) return;
  const short* Bp = B + (size_t)e * N * K;

  const int lane = tid & 63, wid = tid >> 6;
  const int wr = wid >> 2, wc = wid & 3;
  const int lr = lane & 15, lg = lane >> 4;
  const int lrow = lane >> 3;
  const int lcc = ((lane & 7) ^ lrow) << 3;

  if (MODE == 1) {
    if (tid < 128) {
      int r = bm * 128 + tid;
      sRow[tid] = (r < cnt) ? row_map[base + r] : row_map[base];
    }
    __syncthreads();
  }
  int rag[2], rbg[2];
#pragma unroll
  for (int i = 0; i < 2; i++) {
    const int rl = wid * 8 + i * 64 + lrow;
    if (MODE == 2) {
      rag[i] = base + ((bm * 128 + rl < cnt) ? (bm * 128 + rl) : 0);
    } else {
      rag[i] = sRow[rl];
    }
    rbg[i] = bn * 128 + rl;
  }

  f32x4 acc[4][2];
#pragma unroll
  for (int m = 0; m < 4; m++)
#pragma unroll
    for (int n = 0; n < 2; n++) acc[m][n] = (f32x4){0.f, 0.f, 0.f, 0.f};

  const int nk = K >> 6;
  for (int kt = 0; kt < nk; ++kt) {
    __syncthreads();
    const int colk = (kt << 6) + lcc;
#pragma unroll
    for (int i = 0; i < 2; i++) {
      gload_lds16(A + (size_t)rag[i] * K + colk, &sA[(wid * 8 + i * 64) * 64]);
      gload_lds16(Bp + (size_t)rbg[i] * K + colk, &sB[(wid * 8 + i * 64) * 64]);
    }
    __syncthreads();
#pragma unroll
    for (int ks = 0; ks < 2; ks++) {
      const int sw = ((((ks << 2) + lg) ^ (lr & 7)) << 3);
      bf16x8 a[4], b[2];
#pragma unroll
      for (int m = 0; m < 4; m++)
        a[m] = *(const bf16x8*)&sA[(wr * 64 + m * 16 + lr) * 64 + sw];
#pragma unroll
      for (int n = 0; n < 2; n++)
        b[n] = *(const bf16x8*)&sB[(wc * 32 + n * 16 + lr) * 64 + sw];
#pragma unroll
      for (int m = 0; m < 4; m++)
#pragma unroll
        for (int n = 0; n < 2; n++)
          acc[m][n] = __builtin_amdgcn_mfma_f32_16x16x32_bf16(a[m], b[n], acc[m][n], 0, 0, 0);
    }
  }

#pragma unroll
  for (int m = 0; m < 4; m++) {
    const int rl = wr * 64 + m * 16 + lg * 4;
#pragma unroll
    for (int n = 0; n < 2; n++) {
      f32x4 v = acc[m][n];
      const int col = bn * 128 + wc * 32 + n * 16 + lr;
#pragma unroll
      for (int j = 0; j < 4; j++) {
        const int rloc = bm * 128 + rl + j;
        if (rloc >= cnt) continue;
        const size_t idx = (size_t)(base + rloc) * N + col;
        float xv = v[j];
        if (EPI == 1) {
          float s = xv / (1.f + __expf(-xv));
          ((short*)C)[idx] = f2bf(s);
        } else {
          ((short*)C)[idx] = f2bf(xv);
        }
      }
    }
  }
}

// ---------- MoE gating FP64, FUSED with rms->xn write ----------
__global__ __launch_bounds__(256) void gate_k(const float* __restrict__ H,
                                              const float* __restrict__ w3,
                                              const float* __restrict__ gw,
                                              short* __restrict__ xn,
                                              int* counts, int* tok_e, int* tok_s,
                                              float* tok_g) {
  const int token = blockIdx.x * 4 + (threadIdx.x >> 6);
  const int lane = threadIdx.x & 63;
  const float* xr = H + (size_t)token * 1024;
  float4 xv4[4], w34[4];
  double a[8] = {0, 0, 0, 0, 0, 0, 0, 0};
  double ss = 0.0;
#pragma unroll
  for (int i = 0; i < 4; i++) {
    xv4[i] = *(const float4*)&xr[i * 256 + lane * 4];
    w34[i] = *(const float4*)&w3[i * 256 + lane * 4];
    float4 xv = xv4[i], w3v = w34[i];
    ss += (double)xv.x * xv.x + (double)xv.y * xv.y + (double)xv.z * xv.z + (double)xv.w * xv.w;
    double xw0 = (double)xv.x * (double)w3v.x, xw1 = (double)xv.y * (double)w3v.y;
    double xw2 = (double)xv.z * (double)w3v.z, xw3 = (double)xv.w * (double)w3v.w;
#pragma unroll
    for (int e = 0; e < 8; e++) {
      float4 wv = *(const float4*)&gw[e * 1024 + i * 256 + lane * 4];
      a[e] += xw0 * wv.x + xw1 * wv.y + xw2 * wv.z + xw3 * wv.w;
    }
  }
#pragma unroll
  for (int off = 32; off; off >>= 1) ss += __shfl_xor(ss, off);
#pragma unroll
  for (int off = 32; off; off >>= 1) {
#pragma unroll
    for (int e = 0; e < 8; e++) a[e] += __shfl_down(a[e], off);
  }
  const double rs_d = 1.0 / sqrt(ss * (1.0 / 1024.0) + 1e-5);
  const float rs = (float)rs_d;
#pragma unroll
  for (int i = 0; i < 4; i++) {
    s16x4 ob;
    ob.x = f2bf(xv4[i].x * rs * w34[i].x);
    ob.y = f2bf(xv4[i].y * rs * w34[i].y);
    ob.z = f2bf(xv4[i].z * rs * w34[i].z);
    ob.w = f2bf(xv4[i].w * rs * w34[i].w);
    *(s16x4*)&xn[(size_t)token * 1024 + i * 256 + lane * 4] = ob;
  }
  if (lane == 0) {
    double v0 = a[0]; int i0 = 0;
#pragma unroll
    for (int e = 1; e < 8; e++) if (a[e] > v0) { v0 = a[e]; i0 = e; }
    double v1 = -1e300; int i1 = 0;
#pragma unroll
    for (int e = 0; e < 8; e++) if (e != i0 && a[e] > v1) { v1 = a[e]; i1 = e; }
    double t = exp((v1 - v0) * rs_d);
    double g0 = 1.0 / (1.0 + t);
    int s0 = atomicAdd(&counts[i0], 1);
    int s1 = atomicAdd(&counts[i1], 1);
    tok_e[2 * token] = i0; tok_e[2 * token + 1] = i1;
    tok_s[2 * token] = s0; tok_s[2 * token + 1] = s1;
    tok_g[2 * token] = (float)g0; tok_g[2 * token + 1] = (float)(1.0 - g0);
  }
}

__global__ void offsets_k(int* counts, int* offs) {
  if (threadIdx.x == 0 && blockIdx.x == 0) {
    counts[8] = 4096;
    int s = 0;
    for (int e = 0; e < 9; e++) { offs[e] = s; s += counts[e]; }
  }
}

__global__ __launch_bounds__(256) void build_rows_k(const int* __restrict__ offs,
                                                    const int* __restrict__ tok_e,
                                                    const int* __restrict__ tok_s,
                                                    int* __restrict__ row_map,
                                                    int* __restrict__ tok_row) {
  int n = blockIdx.x * 256 + threadIdx.x;
  int e0 = tok_e[2 * n], e1 = tok_e[2 * n + 1];
  int r0 = offs[e0] + tok_s[2 * n], r1 = offs[e1] + tok_s[2 * n + 1];
  row_map[r0] = n; row_map[r1] = n;
  row_map[8192 + n] = n;
  tok_row[2 * n] = r0; tok_row[2 * n + 1] = r1;
}

// ---------- final combine: out = H + eo_shared + g0*eo0 + g1*eo1 (eo bf16) ----------
__global__ __launch_bounds__(256) void combine_k(const float* __restrict__ H,
                                                 const short* __restrict__ eo,
                                                 const int* __restrict__ tok_row,
                                                 const float* __restrict__ tok_g,
                                                 float* __restrict__ out) {
  const int n = blockIdx.x, t = threadIdx.x;
  const int r0 = tok_row[2 * n], r1 = tok_row[2 * n + 1];
  const float g0 = tok_g[2 * n], g1 = tok_g[2 * n + 1];
  const size_t ib = (size_t)n * 1024 + t * 4;
  float4 hv = *(const float4*)&H[ib];
  s16x4 sv = *(const s16x4*)&eo[(size_t)(8192 + n) * 1024 + t * 4];
  s16x4 a0 = *(const s16x4*)&eo[(size_t)r0 * 1024 + t * 4];
  s16x4 a1 = *(const s16x4*)&eo[(size_t)r1 * 1024 + t * 4];
  float4 ov;
  ov.x = hv.x + bf2f(sv.x) + g0 * bf2f(a0.x) + g1 * bf2f(a1.x);
  ov.y = hv.y + bf2f(sv.y) + g0 * bf2f(a0.y) + g1 * bf2f(a1.y);
  ov.z = hv.z + bf2f(sv.z) + g0 * bf2f(a0.z) + g1 * bf2f(a1.z);
  ov.w = hv.w + bf2f(sv.w) + g0 * bf2f(a0.w) + g1 * bf2f(a1.w);
  *(float4*)&out[ib] = ov;
}

// ---------- host ----------
extern "C" void kernel_launch(void* const* d_in, const int* in_sizes, int n_in,
                              void* d_out, int out_size, void* d_ws, size_t ws_size,
                              hipStream_t stream) {
  (void)in_sizes; (void)n_in; (void)out_size;
  const float* x     = (const float*)d_in[0];
  const float* enc   = (const float*)d_in[1];
  const float* n1w   = (const float*)d_in[4];
  const float* n2w   = (const float*)d_in[5];
  const float* n3w   = (const float*)d_in[6];
  const float* sa_wq = (const float*)d_in[7];
  const float* sa_wk = (const float*)d_in[8];
  const float* sa_wv = (const float*)d_in[9];
  const float* sa_wo = (const float*)d_in[10];
  const float* ca_wq = (const float*)d_in[11];
  const float* ca_wk = (const float*)d_in[12];
  const float* ca_wv = (const float*)d_in[13];
  const float* ca_wo = (const float*)d_in[14];
  const float* gw    = (const float*)d_in[15];
  const float* e_w1  = (const float*)d_in[16];
  const float* e_w2  = (const float*)d_in[17];
  const float* s_w1  = (const float*)d_in[18];
  const float* s_w2  = (const float*)d_in[19];
  float* out = (float*)d_out;

  char* p = (char*)d_ws;
  size_t off = 0;
  auto alloc = [&](size_t bytes) -> void* {
    void* r = p + off;
    off += (bytes + 255) & ~(size_t)255;
    return r;
  };
  short* w_all1 = (short*)alloc(9LL * 4096 * 1024 * 2);
  short* w_all2 = (short*)alloc(9LL * 1024 * 4096 * 2);
  short* xn     = (short*)alloc(4096LL * 1024 * 2);
  char*  U      = (char*)alloc(12288LL * 4096 * 2);
  short* hbuf   = (short*)U;
  float* Hb     = (float*)alloc(4096LL * 1024 * 4);
  short* eo     = (short*)alloc(12288LL * 1024 * 2);
  short* xh     = (short*)alloc(4096LL * 1024 * 2);
  short* xl     = (short*)alloc(4096LL * 1024 * 2);
  short* wsplH  = (short*)alloc(8650752LL * 2);
  short* wsplL  = (short*)alloc(8650752LL * 2);
  int*   counts = (int*)alloc(9 * 4);
  int*   offs   = (int*)alloc(9 * 4);
  int*   tok_e  = (int*)alloc(4096LL * 2 * 4);
  int*   tok_s  = (int*)alloc(4096LL * 2 * 4);
  float* tok_g  = (float*)alloc(4096LL * 2 * 4);
  int*   tok_row= (int*)alloc(4096LL * 2 * 4);
  int*   row_map= (int*)alloc(12288LL * 4);
  if (off > ws_size) return;

  short* wQKVh = wsplH;
  short* wQKVl = wsplL;
  short* wOh   = wsplH + 3145728;
  short* wOl   = wsplL + 3145728;
  short* wCQh  = wsplH + 4194304;
  short* wCQl  = wsplL + 4194304;
  short* wCKVh = wsplH + 5242880;
  short* wCKVl = wsplL + 5242880;
  short* wCOh  = wsplH + 7340032;
  short* wCOl  = wsplL + 7340032;
  short* ench  = wsplH + 8388608;
  short* encl  = wsplL + 8388608;

  short* qkvh = (short*)U;
  short* qkvl = qkvh + 4096LL * 3072;
  short* crossQh = (short*)U;
  short* crossQl = crossQh + 4096LL * 1024;
  short* encKVh  = crossQl + 4096LL * 1024;
  short* encKVl  = encKVh + 256LL * 2048;

  auto cvt = [&](const float* s, short* d, long n) {
    long n4 = n / 4;
    long g = (n4 + 255) / 256;
    int grid = (int)(g > 4096 ? 4096 : g);
    cvt_k<<<grid, 256, 0, stream>>>(s, d, n4);
  };

  cvt2multi_k<<<dim3(1024, 9), 256, 0, stream>>>(sa_wq, sa_wk, sa_wv, sa_wo,
      ca_wq, ca_wk, ca_wv, ca_wo, enc, wsplH, wsplL);

  cvt(e_w1, w_all1, 8L * 4096 * 1024);
  cvt(s_w1, w_all1 + 8L * 4096 * 1024, 4096L * 1024);
  cvt(e_w2, w_all2, 8L * 1024 * 4096);
  cvt(s_w2, w_all2 + 8L * 1024 * 4096, 1024L * 4096);

  // ---- self attention ----
  rms2_k<<<4096, 256, 0, stream>>>(x, n1w, xh, xl);
  gemm3_k<3><<<dim3(24, 32), 512, 0, stream>>>(xh, xl, wQKVh, wQKVl, nullptr, nullptr,
      qkvh, qkvl, 4096, 3072, 1024);
  attn3_k<true><<<1024, 256, 0, stream>>>(qkvh, qkvl, 3072,
      qkvh + 1024, qkvl + 1024, 3072, qkvh + 2048, qkvl + 2048, 3072,
      xh, xl, 1024, 1024, 1024, 0.125f);
  gemm3_k<2><<<dim3(8, 32), 512, 0, stream>>>(xh, xl, wOh, wOl, Hb, x,
      nullptr, nullptr, 4096, 1024, 1024);

  // ---- cross attention ----
  rms2_k<<<4096, 256, 0, stream>>>(Hb, n2w, xh, xl);
  gemm3_k<3><<<dim3(8, 32), 512, 0, stream>>>(xh, xl, wCQh, wCQl, nullptr, nullptr,
      crossQh, crossQl, 4096, 1024, 1024);
  gemm3_k<3><<<dim3(16, 2), 512, 0, stream>>>(ench, encl, wCKVh, wCKVl, nullptr, nullptr,
      encKVh, encKVl, 256, 2048, 1024);
  attn3_k<false><<<1024, 256, 0, stream>>>(crossQh, crossQl, 1024,
      encKVh, encKVl, 2048, encKVh + 1024, encKVl + 1024, 2048,
      xh, xl, 1024, 1024, 64, 0.125f);
  gemm3_k<2><<<dim3(8, 32), 512, 0, stream>>>(xh, xl, wCOh, wCOl, Hb, Hb,
      nullptr, nullptr, 4096, 1024, 1024);

  // ---- MoE: fused fp64 gate + rms->xn; 9-expert bf16 MFMA, BK=64, 8-wave ----
  hipMemsetAsync(counts, 0, 8 * sizeof(int), stream);
  gate_k<<<1024, 256, 0, stream>>>(Hb, n3w, gw, xn, counts, tok_e, tok_s, tok_g);
  offsets_k<<<1, 1, 0, stream>>>(counts, offs);
  build_rows_k<<<16, 256, 0, stream>>>(offs, tok_e, tok_s, row_map, tok_row);
  gemm_bt_k<1, 1><<<dim3(32, 32, 9), 512, 0, stream>>>(xn, w_all1, hbuf,
      4096, 4096, 1024, row_map, counts, offs);
  gemm_bt_k<3, 2><<<dim3(8, 32, 9), 512, 0, stream>>>(hbuf, w_all2, eo,
      4096, 1024, 4096, row_map, counts, offs);

  combine_k<<<4096, 256, 0, stream>>>(Hb, eo, tok_row, tok_g, out);
}